// Round 2
// baseline (256.708 us; speedup 1.0000x reference)
//
#include <hip/hip_runtime.h>
#include <hip/hip_bf16.h>

// GAT layer: out = h = x @ W^T  (N=200000 x 128, fp32 in / fp32 out), then
// E=500 edges: out[dst] += 0.1 * leaky_relu(attn, 0.2) * h[src].
//
// Kernel 1: fp32 loads -> bf16 MFMA (16x16x32) -> fp32 stores. Memory-bound.
// Kernel 2: per-edge apply, all-fp32; representative-dst scheme = single
//           writer per output row, no atomics. edge_index int64-vs-int32
//           layout autodetected at runtime.

typedef __attribute__((ext_vector_type(8))) short bf16x8;   // 8 bf16 = 4 VGPRs
typedef __attribute__((ext_vector_type(4))) float f32x4;

#define W_PAD 136   // 128 + 8 bf16; 272 B row stride (16B-aligned)

__global__ __launch_bounds__(256) void gat_gemm_kernel(
    const float* __restrict__ x,
    const float* __restrict__ W,
    float* __restrict__ out,
    int N) {
  __shared__ __hip_bfloat16 Ws[128 * W_PAD];   // 34816 B

  const int t = threadIdx.x;

  // Stage W (128x128 fp32 = 64 KB) into LDS as bf16, float4 loads.
  #pragma unroll
  for (int it = 0; it < 16; ++it) {
    int seg = t + it * 256;            // 0..4095 float4 segments
    int row = seg >> 5;                // 32 segments per 128-col row
    int off = (seg & 31) * 4;
    float4 v = *reinterpret_cast<const float4*>(&W[row * 128 + off]);
    union { ushort4 u4; __hip_bfloat16 h[4]; } wpk;
    wpk.h[0] = __float2bfloat16(v.x);
    wpk.h[1] = __float2bfloat16(v.y);
    wpk.h[2] = __float2bfloat16(v.z);
    wpk.h[3] = __float2bfloat16(v.w);
    *reinterpret_cast<ushort4*>(&Ws[row * W_PAD + off]) = wpk.u4;
  }
  __syncthreads();

  const int wave = t >> 6;
  const int lane = t & 63;
  const int m = lane & 15;     // A row / D col index within 16-tile
  const int q = lane >> 4;     // quad 0..3

  const long rowbase = (long)blockIdx.x * 64 + (long)wave * 16;
  if (rowbase >= N) return;

  long arow = rowbase + m;
  if (arow >= N) arow = N - 1;               // clamp (stores guarded)
  const float* xrow = x + arow * 128;

  // A fragments: lane holds x[arow][s*32 + q*8 .. +7], converted to bf16
  bf16x8 afrag[4];
  #pragma unroll
  for (int s = 0; s < 4; ++s) {
    float4 v0 = *reinterpret_cast<const float4*>(xrow + s * 32 + q * 8);
    float4 v1 = *reinterpret_cast<const float4*>(xrow + s * 32 + q * 8 + 4);
    union { bf16x8 v; __hip_bfloat16 h[8]; } u;
    u.h[0] = __float2bfloat16(v0.x); u.h[1] = __float2bfloat16(v0.y);
    u.h[2] = __float2bfloat16(v0.z); u.h[3] = __float2bfloat16(v0.w);
    u.h[4] = __float2bfloat16(v1.x); u.h[5] = __float2bfloat16(v1.y);
    u.h[6] = __float2bfloat16(v1.z); u.h[7] = __float2bfloat16(v1.w);
    afrag[s] = u.v;
  }

  f32x4 acc[8];
  #pragma unroll
  for (int nt = 0; nt < 8; ++nt) acc[nt] = (f32x4){0.f, 0.f, 0.f, 0.f};

  // D[m][n] = sum_k A[m][k] * B[k][n],  B[k][n] = W[n][k]
  #pragma unroll
  for (int s = 0; s < 4; ++s) {
    #pragma unroll
    for (int nt = 0; nt < 8; ++nt) {
      bf16x8 bfrag = *reinterpret_cast<const bf16x8*>(
          &Ws[(nt * 16 + m) * W_PAD + s * 32 + q * 8]);
      acc[nt] = __builtin_amdgcn_mfma_f32_16x16x32_bf16(afrag[s], bfrag,
                                                        acc[nt], 0, 0, 0);
    }
  }

  // D element (reg r, lane) -> row = rowbase + q*4 + r, col = nt*16 + m
  #pragma unroll
  for (int nt = 0; nt < 8; ++nt) {
    #pragma unroll
    for (int r = 0; r < 4; ++r) {
      long orow = rowbase + q * 4 + r;
      if (orow < N)
        out[orow * 128 + nt * 16 + m] = acc[nt][r];
    }
  }
}

// One block (128 threads) per edge. Only the representative edge (lowest
// index among edges sharing its dst) writes; it accumulates all duplicates'
// contributions in fp32, then a single RMW on out[dst] row. All-fp32 math.
__global__ __launch_bounds__(128) void gat_edge_kernel(
    const float* __restrict__ x,
    const int* __restrict__ eidx,          // [2,E]: int32, or int64 (detected)
    const float* __restrict__ W,
    const float* __restrict__ a,           // [4, 64] fp32
    float* __restrict__ out,
    int E) {
  __shared__ int es[2048];

  // Detect int64 little-endian layout: high words (odd positions) all zero.
  int or_odd = 0;
  #pragma unroll
  for (int k = 0; k < 16; ++k) or_odd |= eidx[2 * k + 1];
  const bool is64 = (or_odd == 0);

  const int words = 2 * E * (is64 ? 2 : 1);
  const bool staged = (words <= 2048);
  const int t = threadIdx.x;
  if (staged)
    for (int i = t; i < words; i += 128) es[i] = eidx[i];
  __syncthreads();

  auto EDGE = [&](int pos) -> int {
    int idx = is64 ? 2 * pos : pos;
    return staged ? es[idx] : eidx[idx];
  };

  const int e = blockIdx.x;
  const int dst = EDGE(E + e);
  for (int e2 = 0; e2 < e; ++e2)
    if (EDGE(E + e2) == dst) return;       // not representative (uniform exit)

  const int c = t;                         // feature 0..127
  const int hd = c >> 5;                   // head
  const int d = c & 31;                    // dim within head
  const float a_s = a[hd * 64 + d];
  const float a_d = a[hd * 64 + 32 + d];

  float acc = 0.f;
  for (int e2 = e; e2 < E; ++e2) {
    if (EDGE(E + e2) != dst) continue;     // block-uniform
    const int src = EDGE(e2);
    float hs = 0.f, hdt = 0.f;
    const float* wr = W + (long)c * 128;
    const float* xs = x + (long)src * 128;
    const float* xd = x + (long)dst * 128;
    for (int k = 0; k < 128; ++k) {
      float w = wr[k];
      hs  = fmaf(w, xs[k], hs);
      hdt = fmaf(w, xd[k], hdt);
    }
    // attn[hd] = sum over the 32 dims of this head (butterfly within head)
    float term = a_s * hs + a_d * hdt;
    term += __shfl_xor(term, 16);
    term += __shfl_xor(term, 8);
    term += __shfl_xor(term, 4);
    term += __shfl_xor(term, 2);
    term += __shfl_xor(term, 1);
    float attn = term >= 0.f ? term : 0.2f * term;   // leaky_relu(0.2)
    acc += 0.1f * attn * hs;
  }

  const long o = (long)dst * 128 + c;
  out[o] = out[o] + acc;
}

extern "C" void kernel_launch(void* const* d_in, const int* in_sizes, int n_in,
                              void* d_out, int out_size, void* d_ws, size_t ws_size,
                              hipStream_t stream) {
  const float* x  = (const float*)d_in[0];
  const int* eidx = (const int*)d_in[1];
  const float* W  = (const float*)d_in[2];
  const float* a  = (const float*)d_in[3];
  float* out = (float*)d_out;

  const int N = in_sizes[0] / 128;   // 200000
  const int E = in_sizes[1] / 2;     // 500

  const int blocks = (N + 63) / 64;
  gat_gemm_kernel<<<blocks, 256, 0, stream>>>(x, W, out, N);
  gat_edge_kernel<<<E, 128, 0, stream>>>(x, eidx, W, a, out, E);
}

// Round 3
// 207.081 us; speedup vs baseline: 1.2397x; 1.2397x over previous
//
#include <hip/hip_runtime.h>
#include <hip/hip_bf16.h>

// GAT layer: out = h = x @ W^T  (N=200000 x 128, fp32 in / fp32 out), then
// E=500 edges: out[dst] += 0.1 * leaky_relu(attn, 0.2) * h[src].
//
// K1: fp32 -> bf16 MFMA GEMM (16x16x32), 256 rows/block (W staged once per
//     block, reused across 4 row-subtiles). Memory-bound target ~33 us.
// K2 (phase A): per-edge attn from h (read from `out`), contribution vectors
//     into d_ws. All h reads complete before any update -> race-free.
// K3 (phase B): fp32 atomicAdd scatter of contributions into out[dst];
//     hardware accumulates duplicate dst rows.

typedef __attribute__((ext_vector_type(8))) short bf16x8;   // 8 bf16 = 4 VGPRs
typedef __attribute__((ext_vector_type(4))) float f32x4;

#define W_PAD 136   // 128 + 8 bf16; 272 B row stride (16B-aligned)

__global__ __launch_bounds__(256, 4) void gat_gemm_kernel(
    const float* __restrict__ x,
    const float* __restrict__ W,
    float* __restrict__ out,
    int N) {
  __shared__ __hip_bfloat16 Ws[128 * W_PAD];   // 34816 B

  const int t = threadIdx.x;

  // Stage W (128x128 fp32 = 64 KB) into LDS as bf16, float4 loads.
  #pragma unroll
  for (int it = 0; it < 16; ++it) {
    int seg = t + it * 256;            // 0..4095 float4 segments
    int row = seg >> 5;                // 32 segments per 128-col row
    int off = (seg & 31) * 4;
    float4 v = *reinterpret_cast<const float4*>(&W[row * 128 + off]);
    union { ushort4 u4; __hip_bfloat16 h[4]; } wpk;
    wpk.h[0] = __float2bfloat16(v.x);
    wpk.h[1] = __float2bfloat16(v.y);
    wpk.h[2] = __float2bfloat16(v.z);
    wpk.h[3] = __float2bfloat16(v.w);
    *reinterpret_cast<ushort4*>(&Ws[row * W_PAD + off]) = wpk.u4;
  }
  __syncthreads();

  const int wave = t >> 6;
  const int lane = t & 63;
  const int m = lane & 15;     // A row / D col index within 16-tile
  const int q = lane >> 4;     // quad 0..3

  // 4 row-subtiles of 64 per block: W staged once, reused 4x.
  for (int sub = 0; sub < 4; ++sub) {
    const long rowbase = (long)blockIdx.x * 256 + sub * 64 + (long)wave * 16;
    if (rowbase >= N) break;                 // per-wave uniform; no syncs below

    const float* xrow = x + (rowbase + m) * 128;

    // A fragments: lane holds x[rowbase+m][s*32 + q*8 .. +7] as bf16.
    bf16x8 afrag[4];
    #pragma unroll
    for (int s = 0; s < 4; ++s) {
      float4 v0 = *reinterpret_cast<const float4*>(xrow + s * 32 + q * 8);
      float4 v1 = *reinterpret_cast<const float4*>(xrow + s * 32 + q * 8 + 4);
      union { bf16x8 v; __hip_bfloat16 h[8]; } u;
      u.h[0] = __float2bfloat16(v0.x); u.h[1] = __float2bfloat16(v0.y);
      u.h[2] = __float2bfloat16(v0.z); u.h[3] = __float2bfloat16(v0.w);
      u.h[4] = __float2bfloat16(v1.x); u.h[5] = __float2bfloat16(v1.y);
      u.h[6] = __float2bfloat16(v1.z); u.h[7] = __float2bfloat16(v1.w);
      afrag[s] = u.v;
    }

    f32x4 acc[8];
    #pragma unroll
    for (int nt = 0; nt < 8; ++nt) acc[nt] = (f32x4){0.f, 0.f, 0.f, 0.f};

    // D[m][n] = sum_k A[m][k] * B[k][n],  B[k][n] = W[n][k]
    #pragma unroll
    for (int s = 0; s < 4; ++s) {
      #pragma unroll
      for (int nt = 0; nt < 8; ++nt) {
        bf16x8 bfrag = *reinterpret_cast<const bf16x8*>(
            &Ws[(nt * 16 + m) * W_PAD + s * 32 + q * 8]);
        acc[nt] = __builtin_amdgcn_mfma_f32_16x16x32_bf16(afrag[s], bfrag,
                                                          acc[nt], 0, 0, 0);
      }
    }

    // D element (reg r, lane) -> row = rowbase + q*4 + r, col = nt*16 + m
    // (N % 64 == 0 so full tiles; no store guards needed.)
    #pragma unroll
    for (int nt = 0; nt < 8; ++nt) {
      #pragma unroll
      for (int r = 0; r < 4; ++r)
        out[(rowbase + q * 4 + r) * 128 + nt * 16 + m] = acc[nt][r];
    }
  }
}

__device__ __forceinline__ int detect_i64(const int* eidx) {
  int or_odd = 0;
  #pragma unroll
  for (int k = 0; k < 16; ++k) or_odd |= eidx[2 * k + 1];
  return or_odd == 0;   // int64 little-endian: high words all zero
}

// Phase A: one block per edge. Read h rows from `out` (pure read), compute
// attn, write contribution vector 0.1*attn*h_src to ws. No races.
__global__ __launch_bounds__(128) void gat_edge_attn(
    const int* __restrict__ eidx,
    const float* __restrict__ a,       // [4, 64]
    const float* __restrict__ h,       // == out, post-GEMM
    float* __restrict__ contrib,       // [E, 128] in ws
    int E) {
  const int e = blockIdx.x;
  const int c = threadIdx.x;
  const bool is64 = detect_i64(eidx);
  const int src = is64 ? eidx[2 * e] : eidx[e];
  const int dst = is64 ? eidx[2 * (E + e)] : eidx[E + e];

  const float hs = h[(long)src * 128 + c];
  const float hd = h[(long)dst * 128 + c];

  const int head = c >> 5, d = c & 31;
  float term = a[head * 64 + d] * hs + a[head * 64 + 32 + d] * hd;
  // reduce over the 32 lanes of this head (heads occupy 32-lane halves)
  term += __shfl_xor(term, 16);
  term += __shfl_xor(term, 8);
  term += __shfl_xor(term, 4);
  term += __shfl_xor(term, 2);
  term += __shfl_xor(term, 1);
  const float attn = term >= 0.f ? term : 0.2f * term;   // leaky_relu(0.2)

  contrib[(long)e * 128 + c] = 0.1f * attn * hs;
}

// Phase B: atomic scatter-add of contributions (duplicate dst handled by HW).
__global__ __launch_bounds__(128) void gat_edge_scatter(
    const int* __restrict__ eidx,
    const float* __restrict__ contrib,
    float* __restrict__ out,
    int E) {
  const int e = blockIdx.x;
  const int c = threadIdx.x;
  const bool is64 = detect_i64(eidx);
  const int dst = is64 ? eidx[2 * (E + e)] : eidx[E + e];
  atomicAdd(&out[(long)dst * 128 + c], contrib[(long)e * 128 + c]);
}

extern "C" void kernel_launch(void* const* d_in, const int* in_sizes, int n_in,
                              void* d_out, int out_size, void* d_ws, size_t ws_size,
                              hipStream_t stream) {
  const float* x  = (const float*)d_in[0];
  const int* eidx = (const int*)d_in[1];
  const float* W  = (const float*)d_in[2];
  const float* a  = (const float*)d_in[3];
  float* out = (float*)d_out;
  float* contrib = (float*)d_ws;     // needs E*128*4 = 256 KB

  const int N = in_sizes[0] / 128;   // 200000
  const int E = in_sizes[1] / 2;     // 500

  const int blocks = (N + 255) / 256;
  gat_gemm_kernel<<<blocks, 256, 0, stream>>>(x, W, out, N);
  gat_edge_attn<<<E, 128, 0, stream>>>(eidx, a, out, contrib, E);
  gat_edge_scatter<<<E, 128, 0, stream>>>(eidx, contrib, out, E);
}